// Round 4
// baseline (509.332 us; speedup 1.0000x reference)
//
#include <hip/hip_runtime.h>

// Network on 65536 points in a 64^3 grid.
// Insight 1: _ln over a size-1 axis returns exactly its bias (zeros) -> the
//   whole KNN/attention branch contributes exactly 0; ctx channel 1 == 0.
// Insight 2: nbr_interp is "prev point at cur_C[n]+off" -> dense 72^3 grid
//   of prev_F replaces the 191MB index table; dense 9^3 conv + pid scatter.
// Insight 3 (R3 post-mortem): divergent gathers are cheap when TLP is high
//   (~9cyc/wave-gather measured); the nbr3 conv kernels' real problem was
//   1 wave/SIMD (zero latency hiding, serial 27-tap chains).
// R4: 4-way k-split — each point handled by 4 waves (taps 7q..7q+6),
//   LDS-combined partials, register-preloaded indices, predicated zero-fill
//   loads (branch-free fma), wave-uniform weight bases via readfirstlane
//   (s_load weights), k_out epilogue split across all 4 waves.

#define NPTS 65536
#define GD 72
#define GSX (GD*GD)            // 5184
#define GRID_FLOATS (GD*GD*GD) // 373248
#define CD 64
#define CELLS (CD*CD*CD)       // 262144

__global__ __launch_bounds__(256) void k_scatter(const float* __restrict__ prev_F,
                                                 const int* __restrict__ prev_C,
                                                 const int* __restrict__ cur_C,
                                                 float* __restrict__ gridF,
                                                 int* __restrict__ pidg) {
    int m = blockIdx.x * 256 + threadIdx.x;
    int x = prev_C[m*3+0], y = prev_C[m*3+1], z = prev_C[m*3+2];
    gridF[(x+4)*GSX + (y+4)*GD + (z+4)] = prev_F[m];
    int cx = cur_C[m*3+0], cy = cur_C[m*3+1], cz = cur_C[m*3+2];
    pidg[(cx*CD + cy)*CD + cz] = m;           // inverse map (memset to -1)
}

// Dense 9^3 conv over padded prev_F grid. Block = 8x8x8 outputs (2 z/thread),
// 512 blocks -> 2 waves/SIMD. LDS tile 16^3 floats (16KB).
__global__ __launch_bounds__(256) void k_ctx_dense(const float* __restrict__ gridF,
                                                   const int* __restrict__ pidg,
                                                   const float* __restrict__ W_interp,
                                                   const float* __restrict__ b_interp,
                                                   float* __restrict__ ctx) {
    __shared__ float tile[16*16*16];
    int bid = blockIdx.x;
    int bx = (bid >> 6) * 8, by = ((bid >> 3) & 7) * 8, bz = (bid & 7) * 8;
    int t = threadIdx.x;
    #pragma unroll
    for (int rep = 0; rep < 16; ++rep) {
        int i = t + rep*256;
        int a = i >> 8, b = (i >> 4) & 15, c = i & 15;
        tile[i] = gridF[(bx + a)*GSX + (by + b)*GD + (bz + c)];
    }
    __syncthreads();
    int tz = (t & 3) * 2;          // outputs z = tz, tz+1
    int ty = (t >> 2) & 7;
    int tx = t >> 5;
    float acc0 = 0.f, acc1 = 0.f;
    for (int dx = 0; dx < 9; ++dx) {
        for (int dy = 0; dy < 9; ++dy) {
            const float* row = &tile[((tx + dx)*16 + (ty + dy))*16 + tz];
            float2 r0 = *(const float2*)(row);
            float2 r1 = *(const float2*)(row + 2);
            float2 r2 = *(const float2*)(row + 4);
            float2 r3 = *(const float2*)(row + 6);
            float2 r4 = *(const float2*)(row + 8);
            float v[10] = {r0.x,r0.y,r1.x,r1.y,r2.x,r2.y,r3.x,r3.y,r4.x,r4.y};
            const float* wp = &W_interp[(dx*9 + dy)*9];
            #pragma unroll
            for (int dz = 0; dz < 9; ++dz) {
                float w = wp[dz];                   // wave-uniform -> s_load
                acc0 = fmaf(v[dz+0], w, acc0);
                acc1 = fmaf(v[dz+1], w, acc1);
            }
        }
    }
    float bi = b_interp[0];
    int cell = ((bx + tx)*CD + (by + ty))*CD + (bz + tz);
    int2 pids = *(const int2*)(pidg + cell);        // tz even -> 8B aligned
    if (pids.x >= 0) ctx[pids.x] = acc0 + bi;
    if (pids.y >= 0) ctx[pids.y] = acc1 + bi;
}

// ---- nbr3 conv kernels: block = 64 points x 4 k-quarter waves ----
// wave q handles taps k = 7q .. 7q+6 (q=3: 6 taps); partials LDS-combined.

__global__ __launch_bounds__(256) void k_conv0(const int* __restrict__ nbr3,
                                               const float* __restrict__ ctx,
                                               const float* __restrict__ W_conv0,
                                               const float* __restrict__ b_conv0,
                                               const float* __restrict__ Wi00,
                                               const float* __restrict__ bi00,
                                               float* __restrict__ h,
                                               float* __restrict__ o) {
    __shared__ float part[3][32][64];
    int lane = threadIdx.x & 63;
    int q    = threadIdx.x >> 6;
    int kbase = __builtin_amdgcn_readfirstlane(q * 7);   // SGPR -> s_load weights
    int n = blockIdx.x * 64 + lane;
    float cv[7];
    #pragma unroll
    for (int j = 0; j < 7; ++j) {
        int k = kbase + j;
        int raw = (k < 27) ? nbr3[(size_t)n*27 + k] : NPTS;
        cv[j] = (raw < NPTS) ? ctx[raw < NPTS ? raw : 0] : 0.f;  // predicated gather
    }
    float ac[32];
    #pragma unroll
    for (int d = 0; d < 32; ++d) ac[d] = (q == 0) ? b_conv0[d] : 0.f;
    #pragma unroll
    for (int j = 0; j < 7; ++j) {
        const float* wr = &W_conv0[(kbase + j)*64];      // channel 0 only
        #pragma unroll
        for (int d = 0; d < 32; ++d) ac[d] = fmaf(cv[j], wr[d], ac[d]);
    }
    if (q > 0) {
        #pragma unroll
        for (int d = 0; d < 32; ++d) part[q-1][d][lane] = ac[d];
    }
    __syncthreads();
    if (q == 0) {
        #pragma unroll
        for (int d = 0; d < 32; ++d)
            ac[d] = fmaxf(ac[d] + part[0][d][lane] + part[1][d][lane] + part[2][d][lane], 0.f);
        float4* hp = (float4*)(h + (size_t)n*32);
        #pragma unroll
        for (int w = 0; w < 8; ++w) hp[w] = make_float4(ac[w*4], ac[w*4+1], ac[w*4+2], ac[w*4+3]);
        float ov[8];
        #pragma unroll
        for (int j = 0; j < 8; ++j) {
            float tt = bi00[j];
            #pragma unroll
            for (int d = 0; d < 32; ++d) tt = fmaf(ac[d], Wi00[d*8 + j], tt);
            ov[j] = fmaxf(tt, 0.f);
        }
        float4* op = (float4*)(o + (size_t)n*8);
        op[0] = make_float4(ov[0], ov[1], ov[2], ov[3]);
        op[1] = make_float4(ov[4], ov[5], ov[6], ov[7]);
    }
}

// o0a = relu(conv(o, Wi01)+bi01) (8->8); o1a = relu(conv(h, Wi10)+bi10) (32->8)
__global__ __launch_bounds__(256) void k_mid(const int* __restrict__ nbr3,
                                             const float* __restrict__ h,
                                             const float* __restrict__ o,
                                             const float* __restrict__ Wi01,
                                             const float* __restrict__ bi01,
                                             const float* __restrict__ Wi10,
                                             const float* __restrict__ bi10,
                                             float* __restrict__ o0a,
                                             float* __restrict__ o1a) {
    __shared__ float part[3][16][64];
    int lane = threadIdx.x & 63;
    int q    = threadIdx.x >> 6;
    int kbase = __builtin_amdgcn_readfirstlane(q * 7);
    int n = blockIdx.x * 64 + lane;
    const float4 z4 = make_float4(0.f, 0.f, 0.f, 0.f);
    int  idxs[7]; bool acts[7];
    #pragma unroll
    for (int j = 0; j < 7; ++j) {
        int k = kbase + j;
        int raw = (k < 27) ? nbr3[(size_t)n*27 + k] : NPTS;
        acts[j] = raw < NPTS;
        idxs[j] = acts[j] ? raw : 0;
    }
    float ac[16];                                   // [0..8)=a0, [8..16)=a1
    #pragma unroll
    for (int d = 0; d < 8; ++d) { ac[d] = (q==0)? bi01[d] : 0.f; ac[8+d] = (q==0)? bi10[d] : 0.f; }
    float4 bo[2][2], bh[2][8];
    auto loadtap = [&](int J, int S) {
        const float4* op_ = (const float4*)(o + (size_t)idxs[J]*8);
        const float4* hp_ = (const float4*)(h + (size_t)idxs[J]*32);
        bool a_ = acts[J];
        bo[S][0] = a_ ? op_[0] : z4;  bo[S][1] = a_ ? op_[1] : z4;
        #pragma unroll
        for (int w = 0; w < 8; ++w) bh[S][w] = a_ ? hp_[w] : z4;
    };
    loadtap(0, 0);
    #pragma unroll
    for (int j = 0; j < 7; ++j) {
        const int s = j & 1;
        if (j + 1 < 7) loadtap(j + 1, s ^ 1);       // 2-deep pipeline
        float oc[8] = {bo[s][0].x, bo[s][0].y, bo[s][0].z, bo[s][0].w,
                       bo[s][1].x, bo[s][1].y, bo[s][1].z, bo[s][1].w};
        const float* w0 = &Wi01[(kbase + j)*64];
        #pragma unroll
        for (int c = 0; c < 8; ++c)
            #pragma unroll
            for (int d = 0; d < 8; ++d) ac[d] = fmaf(oc[c], w0[c*8 + d], ac[d]);
        const float* w1 = &Wi10[(kbase + j)*256];
        #pragma unroll
        for (int w = 0; w < 8; ++w) {
            float hc[4] = {bh[s][w].x, bh[s][w].y, bh[s][w].z, bh[s][w].w};
            #pragma unroll
            for (int c = 0; c < 4; ++c)
                #pragma unroll
                for (int d = 0; d < 8; ++d) ac[8+d] = fmaf(hc[c], w1[(w*4+c)*8 + d], ac[8+d]);
        }
    }
    if (q > 0) {
        #pragma unroll
        for (int d = 0; d < 16; ++d) part[q-1][d][lane] = ac[d];
    }
    __syncthreads();
    if (q == 0) {
        #pragma unroll
        for (int d = 0; d < 16; ++d)
            ac[d] = fmaxf(ac[d] + part[0][d][lane] + part[1][d][lane] + part[2][d][lane], 0.f);
        float4* p0 = (float4*)(o0a + (size_t)n*8);
        p0[0] = make_float4(ac[0], ac[1], ac[2],  ac[3]);
        p0[1] = make_float4(ac[4], ac[5], ac[6],  ac[7]);
        float4* p1 = (float4*)(o1a + (size_t)n*8);
        p1[0] = make_float4(ac[8], ac[9], ac[10], ac[11]);
        p1[1] = make_float4(ac[12],ac[13],ac[14], ac[15]);
    }
}

// o1 = relu(conv(o1a, Wi11)+bi11) (8->16); o0 = relu(o0a@Wi02+bi02) (8->16)
// blk = relu([o0,o1] + h); out = blk @ W_conv1 + b_conv1  (epilogue 4-way split)
__global__ __launch_bounds__(256) void k_out(const int* __restrict__ nbr3,
                                             const float* __restrict__ h,
                                             const float* __restrict__ o0a,
                                             const float* __restrict__ o1a,
                                             const float* __restrict__ Wi11,
                                             const float* __restrict__ bi11,
                                             const float* __restrict__ Wi02,
                                             const float* __restrict__ bi02,
                                             const float* __restrict__ W_conv1,
                                             const float* __restrict__ b_conv1,
                                             float* __restrict__ out) {
    __shared__ float part[3][16][64];
    __shared__ float blkb[32][64];
    int lane = threadIdx.x & 63;
    int q    = threadIdx.x >> 6;
    int kbase = __builtin_amdgcn_readfirstlane(q * 7);
    int n = blockIdx.x * 64 + lane;
    const float4 z4 = make_float4(0.f, 0.f, 0.f, 0.f);
    float4 tv[7][2];
    #pragma unroll
    for (int j = 0; j < 7; ++j) {
        int k = kbase + j;
        int raw = (k < 27) ? nbr3[(size_t)n*27 + k] : NPTS;
        bool a_ = raw < NPTS;
        const float4* rp = (const float4*)(o1a + (size_t)(a_ ? raw : 0)*8);
        tv[j][0] = a_ ? rp[0] : z4;
        tv[j][1] = a_ ? rp[1] : z4;
    }
    float ac[16];
    #pragma unroll
    for (int d = 0; d < 16; ++d) ac[d] = (q == 0) ? bi11[d] : 0.f;
    #pragma unroll
    for (int j = 0; j < 7; ++j) {
        float rc[8] = {tv[j][0].x, tv[j][0].y, tv[j][0].z, tv[j][0].w,
                       tv[j][1].x, tv[j][1].y, tv[j][1].z, tv[j][1].w};
        const float* wr = &Wi11[(kbase + j)*128];
        #pragma unroll
        for (int c = 0; c < 8; ++c)
            #pragma unroll
            for (int d = 0; d < 16; ++d) ac[d] = fmaf(rc[c], wr[c*16 + d], ac[d]);
    }
    if (q > 0) {
        #pragma unroll
        for (int d = 0; d < 16; ++d) part[q-1][d][lane] = ac[d];
    }
    __syncthreads();
    if (q == 0) {
        #pragma unroll
        for (int d = 0; d < 16; ++d)
            ac[d] += part[0][d][lane] + part[1][d][lane] + part[2][d][lane];
        float blk[32];
        const float4* prow = (const float4*)(o0a + (size_t)n*8);
        float4 pa = prow[0], pb = prow[1];
        float pc[8] = {pa.x, pa.y, pa.z, pa.w, pb.x, pb.y, pb.z, pb.w};
        #pragma unroll
        for (int j = 0; j < 16; ++j) {
            float tt = bi02[j];
            #pragma unroll
            for (int c = 0; c < 8; ++c) tt = fmaf(pc[c], Wi02[c*16 + j], tt);
            blk[j] = fmaxf(tt, 0.f);                 // o0
        }
        #pragma unroll
        for (int j = 0; j < 16; ++j) blk[16+j] = fmaxf(ac[j], 0.f);   // o1
        const float4* hrow = (const float4*)(h + (size_t)n*32);
        #pragma unroll
        for (int w = 0; w < 8; ++w) {
            float4 hv = hrow[w];
            blk[w*4+0] += hv.x; blk[w*4+1] += hv.y; blk[w*4+2] += hv.z; blk[w*4+3] += hv.w;
        }
        #pragma unroll
        for (int e = 0; e < 32; ++e) blkb[e][lane] = fmaxf(blk[e], 0.f);
    }
    __syncthreads();
    int q8 = __builtin_amdgcn_readfirstlane(q * 8);  // out-ch base for this wave
    float bl[32];
    #pragma unroll
    for (int e = 0; e < 32; ++e) bl[e] = blkb[e][lane];
    float oacc[8];
    #pragma unroll
    for (int d = 0; d < 8; ++d) oacc[d] = b_conv1[q8 + d];
    #pragma unroll
    for (int e = 0; e < 32; ++e)
        #pragma unroll
        for (int d = 0; d < 8; ++d) oacc[d] = fmaf(bl[e], W_conv1[e*32 + q8 + d], oacc[d]);
    float4* outp = (float4*)(out + (size_t)n*32 + q8);
    outp[0] = make_float4(oacc[0], oacc[1], oacc[2], oacc[3]);
    outp[1] = make_float4(oacc[4], oacc[5], oacc[6], oacc[7]);
}

extern "C" void kernel_launch(void* const* d_in, const int* in_sizes, int n_in,
                              void* d_out, int out_size, void* d_ws, size_t ws_size,
                              hipStream_t stream) {
    (void)in_sizes; (void)n_in; (void)out_size; (void)ws_size;
    const float* prev_F   = (const float*)d_in[0];
    const int*   prev_C   = (const int*)d_in[1];
    const int*   cur_C    = (const int*)d_in[2];
    // d_in[3] = nbr_interp  (unused: reconstructed via dense grid)
    const int*   nbr3     = (const int*)d_in[4];
    // d_in[5] = knn_idx     (unused: attention branch is exactly zero)
    const float* W_interp = (const float*)d_in[6];
    const float* b_interp = (const float*)d_in[7];
    const float* W_conv0  = (const float*)d_in[8];
    const float* b_conv0  = (const float*)d_in[9];
    const float* W_conv1  = (const float*)d_in[10];
    const float* b_conv1  = (const float*)d_in[11];
    const float* Wi00     = (const float*)d_in[12];
    const float* bi00     = (const float*)d_in[13];
    const float* Wi01     = (const float*)d_in[14];
    const float* bi01     = (const float*)d_in[15];
    const float* Wi02     = (const float*)d_in[16];
    const float* bi02     = (const float*)d_in[17];
    const float* Wi10     = (const float*)d_in[18];
    const float* bi10     = (const float*)d_in[19];
    const float* Wi11     = (const float*)d_in[20];
    const float* bi11     = (const float*)d_in[21];
    // d_in[22..33]: attention + LN params, all unused (branch == 0 exactly)

    float* ws    = (float*)d_ws;
    float* gridF = ws;                      // 373248 floats (72^3)
    int*   pidg  = (int*)(ws + 373248);     // 262144 ints (64^3 cell -> point id)
    float* ctx   = ws + 635392;             // 65536
    float* h     = ws + 700928;             // 65536*32
    float* o     = ws + 2798080;            // 65536*8
    float* o0a   = ws + 3322368;            // 65536*8
    float* o1a   = ws + 3846656;            // 65536*8  (end: 4370944 floats = 16.7 MB)
    float* outp  = (float*)d_out;

    hipMemsetAsync(gridF, 0,    GRID_FLOATS*sizeof(float), stream);
    hipMemsetAsync(pidg,  0xFF, CELLS*sizeof(int),         stream);   // -1
    k_scatter  <<<NPTS/256, 256, 0, stream>>>(prev_F, prev_C, cur_C, gridF, pidg);
    k_ctx_dense<<<512,      256, 0, stream>>>(gridF, pidg, W_interp, b_interp, ctx);
    k_conv0    <<<NPTS/64,  256, 0, stream>>>(nbr3, ctx, W_conv0, b_conv0, Wi00, bi00, h, o);
    k_mid      <<<NPTS/64,  256, 0, stream>>>(nbr3, h, o, Wi01, bi01, Wi10, bi10, o0a, o1a);
    k_out      <<<NPTS/64,  256, 0, stream>>>(nbr3, h, o0a, o1a, Wi11, bi11, Wi02, bi02, W_conv1, b_conv1, outp);
}

// Round 5
// 375.823 us; speedup vs baseline: 1.3552x; 1.3552x over previous
//
#include <hip/hip_runtime.h>

// Network on 65536 points in a 64^3 grid.
// Insight 1: _ln over a size-1 axis returns exactly its bias (zeros) -> the
//   whole KNN/attention branch contributes exactly 0; ctx channel 1 == 0.
// Insight 2: nbr_interp is "prev point at cur_C[n]+off" -> dense 72^3 grid
//   of prev_F replaces the 191MB index table; dense 9^3 conv + pid scatter.
// R4 post-mortem: select-predicated loads (load-all-taps + cndmask) and
//   register-array staging (VGPR 168 -> 2 waves/SIMD; suspected scratch)
//   made k_mid 157us, latency-bound (VALU 24%, occ 11%).
// R5: keep 4-way k-split (4096 waves) but dumb-simple exec-masked tap loop
//   (`if (idx<NPTS) { load; fma; }` -> inactive lanes issue NO loads),
//   no register pipelining, __launch_bounds__(256,4) pins VGPR<=128
//   -> 4 waves/SIMD. Weights stay wave-uniform (SGPR kbase -> s_load).

#define NPTS 65536
#define GD 72
#define GSX (GD*GD)            // 5184
#define GRID_FLOATS (GD*GD*GD) // 373248
#define CD 64
#define CELLS (CD*CD*CD)       // 262144

__global__ __launch_bounds__(256) void k_scatter(const float* __restrict__ prev_F,
                                                 const int* __restrict__ prev_C,
                                                 const int* __restrict__ cur_C,
                                                 float* __restrict__ gridF,
                                                 int* __restrict__ pidg) {
    int m = blockIdx.x * 256 + threadIdx.x;
    int x = prev_C[m*3+0], y = prev_C[m*3+1], z = prev_C[m*3+2];
    gridF[(x+4)*GSX + (y+4)*GD + (z+4)] = prev_F[m];
    int cx = cur_C[m*3+0], cy = cur_C[m*3+1], cz = cur_C[m*3+2];
    pidg[(cx*CD + cy)*CD + cz] = m;           // inverse map (memset to -1)
}

// Dense 9^3 conv over padded prev_F grid. Block = 8x8x8 outputs (2 z/thread),
// 512 blocks -> 2 waves/SIMD. LDS tile 16^3 floats (16KB).
__global__ __launch_bounds__(256) void k_ctx_dense(const float* __restrict__ gridF,
                                                   const int* __restrict__ pidg,
                                                   const float* __restrict__ W_interp,
                                                   const float* __restrict__ b_interp,
                                                   float* __restrict__ ctx) {
    __shared__ float tile[16*16*16];
    int bid = blockIdx.x;
    int bx = (bid >> 6) * 8, by = ((bid >> 3) & 7) * 8, bz = (bid & 7) * 8;
    int t = threadIdx.x;
    #pragma unroll
    for (int rep = 0; rep < 16; ++rep) {
        int i = t + rep*256;
        int a = i >> 8, b = (i >> 4) & 15, c = i & 15;
        tile[i] = gridF[(bx + a)*GSX + (by + b)*GD + (bz + c)];
    }
    __syncthreads();
    int tz = (t & 3) * 2;          // outputs z = tz, tz+1
    int ty = (t >> 2) & 7;
    int tx = t >> 5;
    float acc0 = 0.f, acc1 = 0.f;
    for (int dx = 0; dx < 9; ++dx) {
        for (int dy = 0; dy < 9; ++dy) {
            const float* row = &tile[((tx + dx)*16 + (ty + dy))*16 + tz];
            float2 r0 = *(const float2*)(row);
            float2 r1 = *(const float2*)(row + 2);
            float2 r2 = *(const float2*)(row + 4);
            float2 r3 = *(const float2*)(row + 6);
            float2 r4 = *(const float2*)(row + 8);
            float v[10] = {r0.x,r0.y,r1.x,r1.y,r2.x,r2.y,r3.x,r3.y,r4.x,r4.y};
            const float* wp = &W_interp[(dx*9 + dy)*9];
            #pragma unroll
            for (int dz = 0; dz < 9; ++dz) {
                float w = wp[dz];                   // wave-uniform -> s_load
                acc0 = fmaf(v[dz+0], w, acc0);
                acc1 = fmaf(v[dz+1], w, acc1);
            }
        }
    }
    float bi = b_interp[0];
    int cell = ((bx + tx)*CD + (by + ty))*CD + (bz + tz);
    int2 pids = *(const int2*)(pidg + cell);        // tz even -> 8B aligned
    if (pids.x >= 0) ctx[pids.x] = acc0 + bi;
    if (pids.y >= 0) ctx[pids.y] = acc1 + bi;
}

// ---- nbr3 conv kernels: block = 64 points x 4 k-quarter waves ----
// wave q: taps k = 7q..7q+6 (q=3: 6 taps). Exec-masked gathers, LDS-combined
// partials, bias added at the reduce. 1024 blocks -> 4 waves/SIMD.

__global__ __launch_bounds__(256, 4) void k_conv0(const int* __restrict__ nbr3,
                                                  const float* __restrict__ ctx,
                                                  const float* __restrict__ W_conv0,
                                                  const float* __restrict__ b_conv0,
                                                  const float* __restrict__ Wi00,
                                                  const float* __restrict__ bi00,
                                                  float* __restrict__ h,
                                                  float* __restrict__ o) {
    __shared__ int   ln[64*27];          // 6.9KB
    __shared__ float part[3][32][64];    // 24KB
    int tid = threadIdx.x;
    int lane = tid & 63, q = tid >> 6;
    int n0 = blockIdx.x * 64;
    for (int i = tid; i < 64*27; i += 256) ln[i] = nbr3[(size_t)n0*27 + i];
    __syncthreads();
    int kbase = __builtin_amdgcn_readfirstlane(q * 7);
    int n = n0 + lane;
    float ac[32];
    #pragma unroll
    for (int d = 0; d < 32; ++d) ac[d] = 0.f;
    #pragma unroll
    for (int j = 0; j < 7; ++j) {
        int k = kbase + j;
        if (k < 27) {                         // uniform per wave (only q=3,j=6 false)
            int idx = ln[lane*27 + k];
            if (idx < NPTS) {                 // exec-masked: inactive lanes load nothing
                float cv = ctx[idx];
                const float* wr = &W_conv0[k*64];    // channel 0; ch1 input == 0
                #pragma unroll
                for (int d = 0; d < 32; ++d) ac[d] = fmaf(cv, wr[d], ac[d]);
            }
        }
    }
    if (q > 0) {
        #pragma unroll
        for (int d = 0; d < 32; ++d) part[q-1][d][lane] = ac[d];
    }
    __syncthreads();
    if (q == 0) {
        #pragma unroll
        for (int d = 0; d < 32; ++d)
            ac[d] = fmaxf(ac[d] + b_conv0[d] + part[0][d][lane] + part[1][d][lane] + part[2][d][lane], 0.f);
        float4* hp = (float4*)(h + (size_t)n*32);
        #pragma unroll
        for (int w = 0; w < 8; ++w) hp[w] = make_float4(ac[w*4], ac[w*4+1], ac[w*4+2], ac[w*4+3]);
        float ov[8];
        #pragma unroll
        for (int j = 0; j < 8; ++j) {
            float tt = bi00[j];
            #pragma unroll
            for (int d = 0; d < 32; ++d) tt = fmaf(ac[d], Wi00[d*8 + j], tt);
            ov[j] = fmaxf(tt, 0.f);
        }
        float4* op = (float4*)(o + (size_t)n*8);
        op[0] = make_float4(ov[0], ov[1], ov[2], ov[3]);
        op[1] = make_float4(ov[4], ov[5], ov[6], ov[7]);
    }
}

// o0a = relu(conv(o, Wi01)+bi01) (8->8); o1a = relu(conv(h, Wi10)+bi10) (32->8)
__global__ __launch_bounds__(256, 4) void k_mid(const int* __restrict__ nbr3,
                                                const float* __restrict__ h,
                                                const float* __restrict__ o,
                                                const float* __restrict__ Wi01,
                                                const float* __restrict__ bi01,
                                                const float* __restrict__ Wi10,
                                                const float* __restrict__ bi10,
                                                float* __restrict__ o0a,
                                                float* __restrict__ o1a) {
    __shared__ int   ln[64*27];          // 6.9KB
    __shared__ float part[3][16][64];    // 12KB
    int tid = threadIdx.x;
    int lane = tid & 63, q = tid >> 6;
    int n0 = blockIdx.x * 64;
    for (int i = tid; i < 64*27; i += 256) ln[i] = nbr3[(size_t)n0*27 + i];
    __syncthreads();
    int kbase = __builtin_amdgcn_readfirstlane(q * 7);
    int n = n0 + lane;
    float ac[16];                        // [0..8)=a0 (Wi01), [8..16)=a1 (Wi10)
    #pragma unroll
    for (int d = 0; d < 16; ++d) ac[d] = 0.f;
    #pragma unroll
    for (int j = 0; j < 7; ++j) {
        int k = kbase + j;
        if (k < 27) {
            int idx = ln[lane*27 + k];
            if (idx < NPTS) {            // exec-masked: no loads, no fma when inactive
                const float4* orow = (const float4*)(o + (size_t)idx*8);
                float4 oa = orow[0], ob = orow[1];
                const float4* hrow = (const float4*)(h + (size_t)idx*32);
                float4 h0 = hrow[0], h1 = hrow[1], h2 = hrow[2], h3 = hrow[3];
                float4 h4 = hrow[4], h5 = hrow[5], h6 = hrow[6], h7 = hrow[7];
                float oc[8] = {oa.x,oa.y,oa.z,oa.w, ob.x,ob.y,ob.z,ob.w};
                const float* w0 = &Wi01[k*64];
                #pragma unroll
                for (int c = 0; c < 8; ++c)
                    #pragma unroll
                    for (int d = 0; d < 8; ++d) ac[d] = fmaf(oc[c], w0[c*8 + d], ac[d]);
                float hc[32] = {h0.x,h0.y,h0.z,h0.w, h1.x,h1.y,h1.z,h1.w,
                                h2.x,h2.y,h2.z,h2.w, h3.x,h3.y,h3.z,h3.w,
                                h4.x,h4.y,h4.z,h4.w, h5.x,h5.y,h5.z,h5.w,
                                h6.x,h6.y,h6.z,h6.w, h7.x,h7.y,h7.z,h7.w};
                const float* w1 = &Wi10[k*256];
                #pragma unroll
                for (int c = 0; c < 32; ++c)
                    #pragma unroll
                    for (int d = 0; d < 8; ++d) ac[8+d] = fmaf(hc[c], w1[c*8 + d], ac[8+d]);
            }
        }
    }
    if (q > 0) {
        #pragma unroll
        for (int d = 0; d < 16; ++d) part[q-1][d][lane] = ac[d];
    }
    __syncthreads();
    if (q == 0) {
        #pragma unroll
        for (int d = 0; d < 8; ++d) {
            ac[d]   = fmaxf(ac[d]   + bi01[d] + part[0][d][lane]   + part[1][d][lane]   + part[2][d][lane],   0.f);
            ac[8+d] = fmaxf(ac[8+d] + bi10[d] + part[0][8+d][lane] + part[1][8+d][lane] + part[2][8+d][lane], 0.f);
        }
        float4* p0 = (float4*)(o0a + (size_t)n*8);
        p0[0] = make_float4(ac[0], ac[1], ac[2],  ac[3]);
        p0[1] = make_float4(ac[4], ac[5], ac[6],  ac[7]);
        float4* p1 = (float4*)(o1a + (size_t)n*8);
        p1[0] = make_float4(ac[8], ac[9], ac[10], ac[11]);
        p1[1] = make_float4(ac[12],ac[13],ac[14], ac[15]);
    }
}

// o1 = relu(conv(o1a, Wi11)+bi11) (8->16); o0 = relu(o0a@Wi02+bi02) (8->16)
// blk = relu([o0,o1] + h); out = blk @ W_conv1 + b_conv1 (epilogue 4-way split)
__global__ __launch_bounds__(256, 4) void k_out(const int* __restrict__ nbr3,
                                                const float* __restrict__ h,
                                                const float* __restrict__ o0a,
                                                const float* __restrict__ o1a,
                                                const float* __restrict__ Wi11,
                                                const float* __restrict__ bi11,
                                                const float* __restrict__ Wi02,
                                                const float* __restrict__ bi02,
                                                const float* __restrict__ W_conv1,
                                                const float* __restrict__ b_conv1,
                                                float* __restrict__ out) {
    __shared__ int   ln[64*27];          // 6.9KB
    __shared__ float part[3][16][64];    // 12KB
    __shared__ float blkb[32][64];       // 8KB
    int tid = threadIdx.x;
    int lane = tid & 63, q = tid >> 6;
    int n0 = blockIdx.x * 64;
    for (int i = tid; i < 64*27; i += 256) ln[i] = nbr3[(size_t)n0*27 + i];
    __syncthreads();
    int kbase = __builtin_amdgcn_readfirstlane(q * 7);
    int n = n0 + lane;
    float ac[16];
    #pragma unroll
    for (int d = 0; d < 16; ++d) ac[d] = 0.f;
    #pragma unroll
    for (int j = 0; j < 7; ++j) {
        int k = kbase + j;
        if (k < 27) {
            int idx = ln[lane*27 + k];
            if (idx < NPTS) {
                const float4* rp = (const float4*)(o1a + (size_t)idx*8);
                float4 ra = rp[0], rb = rp[1];
                float rc[8] = {ra.x,ra.y,ra.z,ra.w, rb.x,rb.y,rb.z,rb.w};
                const float* wr = &Wi11[k*128];
                #pragma unroll
                for (int c = 0; c < 8; ++c)
                    #pragma unroll
                    for (int d = 0; d < 16; ++d) ac[d] = fmaf(rc[c], wr[c*16 + d], ac[d]);
            }
        }
    }
    if (q > 0) {
        #pragma unroll
        for (int d = 0; d < 16; ++d) part[q-1][d][lane] = ac[d];
    }
    __syncthreads();
    if (q == 0) {
        #pragma unroll
        for (int d = 0; d < 16; ++d)
            ac[d] += bi11[d] + part[0][d][lane] + part[1][d][lane] + part[2][d][lane];
        float blk[32];
        const float4* prow = (const float4*)(o0a + (size_t)n*8);
        float4 pa = prow[0], pb = prow[1];
        float pc[8] = {pa.x,pa.y,pa.z,pa.w, pb.x,pb.y,pb.z,pb.w};
        #pragma unroll
        for (int j = 0; j < 16; ++j) {
            float tt = bi02[j];
            #pragma unroll
            for (int c = 0; c < 8; ++c) tt = fmaf(pc[c], Wi02[c*16 + j], tt);
            blk[j] = fmaxf(tt, 0.f);                 // o0
        }
        #pragma unroll
        for (int j = 0; j < 16; ++j) blk[16+j] = fmaxf(ac[j], 0.f);   // o1
        const float4* hrow = (const float4*)(h + (size_t)n*32);
        #pragma unroll
        for (int w = 0; w < 8; ++w) {
            float4 hv = hrow[w];
            blk[w*4+0] += hv.x; blk[w*4+1] += hv.y; blk[w*4+2] += hv.z; blk[w*4+3] += hv.w;
        }
        #pragma unroll
        for (int e = 0; e < 32; ++e) blkb[e][lane] = fmaxf(blk[e], 0.f);
    }
    __syncthreads();
    int q8 = __builtin_amdgcn_readfirstlane(q * 8);  // out-channel base for this wave
    float oacc[8];
    #pragma unroll
    for (int d = 0; d < 8; ++d) oacc[d] = b_conv1[q8 + d];
    #pragma unroll
    for (int e = 0; e < 32; ++e) {
        float bl = blkb[e][lane];
        #pragma unroll
        for (int d = 0; d < 8; ++d) oacc[d] = fmaf(bl, W_conv1[e*32 + q8 + d], oacc[d]);
    }
    float4* outp = (float4*)(out + (size_t)n*32 + q8);
    outp[0] = make_float4(oacc[0], oacc[1], oacc[2], oacc[3]);
    outp[1] = make_float4(oacc[4], oacc[5], oacc[6], oacc[7]);
}

extern "C" void kernel_launch(void* const* d_in, const int* in_sizes, int n_in,
                              void* d_out, int out_size, void* d_ws, size_t ws_size,
                              hipStream_t stream) {
    (void)in_sizes; (void)n_in; (void)out_size; (void)ws_size;
    const float* prev_F   = (const float*)d_in[0];
    const int*   prev_C   = (const int*)d_in[1];
    const int*   cur_C    = (const int*)d_in[2];
    // d_in[3] = nbr_interp  (unused: reconstructed via dense grid)
    const int*   nbr3     = (const int*)d_in[4];
    // d_in[5] = knn_idx     (unused: attention branch is exactly zero)
    const float* W_interp = (const float*)d_in[6];
    const float* b_interp = (const float*)d_in[7];
    const float* W_conv0  = (const float*)d_in[8];
    const float* b_conv0  = (const float*)d_in[9];
    const float* W_conv1  = (const float*)d_in[10];
    const float* b_conv1  = (const float*)d_in[11];
    const float* Wi00     = (const float*)d_in[12];
    const float* bi00     = (const float*)d_in[13];
    const float* Wi01     = (const float*)d_in[14];
    const float* bi01     = (const float*)d_in[15];
    const float* Wi02     = (const float*)d_in[16];
    const float* bi02     = (const float*)d_in[17];
    const float* Wi10     = (const float*)d_in[18];
    const float* bi10     = (const float*)d_in[19];
    const float* Wi11     = (const float*)d_in[20];
    const float* bi11     = (const float*)d_in[21];
    // d_in[22..33]: attention + LN params, all unused (branch == 0 exactly)

    float* ws    = (float*)d_ws;
    float* gridF = ws;                      // 373248 floats (72^3)
    int*   pidg  = (int*)(ws + 373248);     // 262144 ints (64^3 cell -> point id)
    float* ctx   = ws + 635392;             // 65536
    float* h     = ws + 700928;             // 65536*32
    float* o     = ws + 2798080;            // 65536*8
    float* o0a   = ws + 3322368;            // 65536*8
    float* o1a   = ws + 3846656;            // 65536*8  (end: 4370944 floats = 16.7 MB)
    float* outp  = (float*)d_out;

    hipMemsetAsync(gridF, 0,    GRID_FLOATS*sizeof(float), stream);
    hipMemsetAsync(pidg,  0xFF, CELLS*sizeof(int),         stream);   // -1
    k_scatter  <<<NPTS/256, 256, 0, stream>>>(prev_F, prev_C, cur_C, gridF, pidg);
    k_ctx_dense<<<512,      256, 0, stream>>>(gridF, pidg, W_interp, b_interp, ctx);
    k_conv0    <<<NPTS/64,  256, 0, stream>>>(nbr3, ctx, W_conv0, b_conv0, Wi00, bi00, h, o);
    k_mid      <<<NPTS/64,  256, 0, stream>>>(nbr3, h, o, Wi01, bi01, Wi10, bi10, o0a, o1a);
    k_out      <<<NPTS/64,  256, 0, stream>>>(nbr3, h, o0a, o1a, Wi11, bi11, Wi02, bi02, W_conv1, b_conv1, outp);
}

// Round 8
// 362.808 us; speedup vs baseline: 1.4039x; 1.0359x over previous
//
#include <hip/hip_runtime.h>

// Network on 65536 points in a 64^3 grid.
// Insight 1: _ln over a size-1 axis returns exactly its bias (zeros) -> the
//   whole KNN/attention branch contributes exactly 0; ctx channel 1 == 0.
// Insight 2: nbr_interp is "prev point at cur_C[n]+off" -> dense 72^3 grid
//   of prev_F replaces the 191MB index table; dense 9^3 conv + pid scatter.
// R5 post-mortem: exec-masked taps + 4 waves/SIMD fixed k_mid (157us -> <113);
//   total 509 -> 376. Remaining mine ~40us; harness fills/restores ~330.
// R6 (final squeeze): (a) ctx_dense LDS tile z-stride 16->20 (was ~8-way bank
//   conflict: lanes sharing ty-parity+tz hit one bank at stride 16), (b) one
//   memset: pid map stores pid+1 so gridF+pidg both re-init to 0x00 in a
//   single fill (-1 dispatch), (c) prefetch tap indices into registers.
// [R8 = R6 resubmitted verbatim: R6 and R7 both hit GPUAcquisitionTimeout,
//  no measurement yet; keeping the kernel identical for clean A/B vs R5.]

#define NPTS 65536
#define GD 72
#define GSX (GD*GD)            // 5184
#define GRID_FLOATS (GD*GD*GD) // 373248
#define CD 64
#define CELLS (CD*CD*CD)       // 262144
#define TS 20                  // LDS tile z-stride (bank-conflict pad)

__global__ __launch_bounds__(256) void k_scatter(const float* __restrict__ prev_F,
                                                 const int* __restrict__ prev_C,
                                                 const int* __restrict__ cur_C,
                                                 float* __restrict__ gridF,
                                                 int* __restrict__ pidg) {
    int m = blockIdx.x * 256 + threadIdx.x;
    int x = prev_C[m*3+0], y = prev_C[m*3+1], z = prev_C[m*3+2];
    gridF[(x+4)*GSX + (y+4)*GD + (z+4)] = prev_F[m];
    int cx = cur_C[m*3+0], cy = cur_C[m*3+1], cz = cur_C[m*3+2];
    pidg[(cx*CD + cy)*CD + cz] = m + 1;       // 0 = empty (zero-memset)
}

// Dense 9^3 conv over padded prev_F grid. Block = 8x8x8 outputs (2 z/thread),
// 512 blocks -> 2 waves/SIMD. LDS tile 16x16 rows x stride-20 (20KB).
__global__ __launch_bounds__(256) void k_ctx_dense(const float* __restrict__ gridF,
                                                   const int* __restrict__ pidg,
                                                   const float* __restrict__ W_interp,
                                                   const float* __restrict__ b_interp,
                                                   float* __restrict__ ctx) {
    __shared__ float tile[16*16*TS];
    int bid = blockIdx.x;
    int bx = (bid >> 6) * 8, by = ((bid >> 3) & 7) * 8, bz = (bid & 7) * 8;
    int t = threadIdx.x;
    #pragma unroll
    for (int rep = 0; rep < 16; ++rep) {
        int i = t + rep*256;
        int a = i >> 8, b = (i >> 4) & 15, c = i & 15;
        tile[(a*16 + b)*TS + c] = gridF[(bx + a)*GSX + (by + b)*GD + (bz + c)];
    }
    __syncthreads();
    int tz = (t & 3) * 2;          // outputs z = tz, tz+1
    int ty = (t >> 2) & 7;
    int tx = t >> 5;
    float acc0 = 0.f, acc1 = 0.f;
    for (int dx = 0; dx < 9; ++dx) {
        for (int dy = 0; dy < 9; ++dy) {
            const float* row = &tile[((tx + dx)*16 + (ty + dy))*TS + tz];
            float2 r0 = *(const float2*)(row);          // tz even -> 8B aligned
            float2 r1 = *(const float2*)(row + 2);
            float2 r2 = *(const float2*)(row + 4);
            float2 r3 = *(const float2*)(row + 6);
            float2 r4 = *(const float2*)(row + 8);
            float v[10] = {r0.x,r0.y,r1.x,r1.y,r2.x,r2.y,r3.x,r3.y,r4.x,r4.y};
            const float* wp = &W_interp[(dx*9 + dy)*9];
            #pragma unroll
            for (int dz = 0; dz < 9; ++dz) {
                float w = wp[dz];                   // wave-uniform -> s_load
                acc0 = fmaf(v[dz+0], w, acc0);
                acc1 = fmaf(v[dz+1], w, acc1);
            }
        }
    }
    float bi = b_interp[0];
    int cell = ((bx + tx)*CD + (by + ty))*CD + (bz + tz);
    int2 pids = *(const int2*)(pidg + cell);        // tz even -> 8B aligned
    if (pids.x > 0) ctx[pids.x - 1] = acc0 + bi;
    if (pids.y > 0) ctx[pids.y - 1] = acc1 + bi;
}

// ---- nbr3 conv kernels: block = 64 points x 4 k-quarter waves ----
// wave q: taps k = 7q..7q+6 (q=3: 6 taps). Register-prefetched indices,
// exec-masked gathers, LDS-combined partials. 1024 blocks -> 4 waves/SIMD.

__global__ __launch_bounds__(256, 4) void k_conv0(const int* __restrict__ nbr3,
                                                  const float* __restrict__ ctx,
                                                  const float* __restrict__ W_conv0,
                                                  const float* __restrict__ b_conv0,
                                                  const float* __restrict__ Wi00,
                                                  const float* __restrict__ bi00,
                                                  float* __restrict__ h,
                                                  float* __restrict__ o) {
    __shared__ int   ln[64*27];          // 6.9KB
    __shared__ float part[3][32][64];    // 24KB
    int tid = threadIdx.x;
    int lane = tid & 63, q = tid >> 6;
    int n0 = blockIdx.x * 64;
    for (int i = tid; i < 64*27; i += 256) ln[i] = nbr3[(size_t)n0*27 + i];
    __syncthreads();
    int kbase = __builtin_amdgcn_readfirstlane(q * 7);
    int n = n0 + lane;
    int idxs[7];
    #pragma unroll
    for (int j = 0; j < 7; ++j) {                   // pipelined ds_reads upfront
        int k = kbase + j;
        int kk = (k < 27) ? k : 26;
        int raw = ln[lane*27 + kk];
        idxs[j] = (k < 27) ? raw : NPTS;
    }
    float ac[32];
    #pragma unroll
    for (int d = 0; d < 32; ++d) ac[d] = 0.f;
    #pragma unroll
    for (int j = 0; j < 7; ++j) {
        int k = kbase + j;
        if (k < 27) {                         // wave-uniform (only q=3,j=6 false)
            int idx = idxs[j];
            if (idx < NPTS) {                 // exec-masked: inactive lanes load nothing
                float cv = ctx[idx];
                const float* wr = &W_conv0[k*64];    // channel 0; ch1 input == 0
                #pragma unroll
                for (int d = 0; d < 32; ++d) ac[d] = fmaf(cv, wr[d], ac[d]);
            }
        }
    }
    if (q > 0) {
        #pragma unroll
        for (int d = 0; d < 32; ++d) part[q-1][d][lane] = ac[d];
    }
    __syncthreads();
    if (q == 0) {
        #pragma unroll
        for (int d = 0; d < 32; ++d)
            ac[d] = fmaxf(ac[d] + b_conv0[d] + part[0][d][lane] + part[1][d][lane] + part[2][d][lane], 0.f);
        float4* hp = (float4*)(h + (size_t)n*32);
        #pragma unroll
        for (int w = 0; w < 8; ++w) hp[w] = make_float4(ac[w*4], ac[w*4+1], ac[w*4+2], ac[w*4+3]);
        float ov[8];
        #pragma unroll
        for (int j = 0; j < 8; ++j) {
            float tt = bi00[j];
            #pragma unroll
            for (int d = 0; d < 32; ++d) tt = fmaf(ac[d], Wi00[d*8 + j], tt);
            ov[j] = fmaxf(tt, 0.f);
        }
        float4* op = (float4*)(o + (size_t)n*8);
        op[0] = make_float4(ov[0], ov[1], ov[2], ov[3]);
        op[1] = make_float4(ov[4], ov[5], ov[6], ov[7]);
    }
}

// o0a = relu(conv(o, Wi01)+bi01) (8->8); o1a = relu(conv(h, Wi10)+bi10) (32->8)
__global__ __launch_bounds__(256, 4) void k_mid(const int* __restrict__ nbr3,
                                                const float* __restrict__ h,
                                                const float* __restrict__ o,
                                                const float* __restrict__ Wi01,
                                                const float* __restrict__ bi01,
                                                const float* __restrict__ Wi10,
                                                const float* __restrict__ bi10,
                                                float* __restrict__ o0a,
                                                float* __restrict__ o1a) {
    __shared__ int   ln[64*27];          // 6.9KB
    __shared__ float part[3][16][64];    // 12KB
    int tid = threadIdx.x;
    int lane = tid & 63, q = tid >> 6;
    int n0 = blockIdx.x * 64;
    for (int i = tid; i < 64*27; i += 256) ln[i] = nbr3[(size_t)n0*27 + i];
    __syncthreads();
    int kbase = __builtin_amdgcn_readfirstlane(q * 7);
    int n = n0 + lane;
    int idxs[7];
    #pragma unroll
    for (int j = 0; j < 7; ++j) {
        int k = kbase + j;
        int kk = (k < 27) ? k : 26;
        int raw = ln[lane*27 + kk];
        idxs[j] = (k < 27) ? raw : NPTS;
    }
    float ac[16];                        // [0..8)=a0 (Wi01), [8..16)=a1 (Wi10)
    #pragma unroll
    for (int d = 0; d < 16; ++d) ac[d] = 0.f;
    #pragma unroll
    for (int j = 0; j < 7; ++j) {
        int k = kbase + j;
        if (k < 27) {
            int idx = idxs[j];
            if (idx < NPTS) {            // exec-masked: no loads, no fma when inactive
                const float4* orow = (const float4*)(o + (size_t)idx*8);
                float4 oa = orow[0], ob = orow[1];
                const float4* hrow = (const float4*)(h + (size_t)idx*32);
                float4 h0 = hrow[0], h1 = hrow[1], h2 = hrow[2], h3 = hrow[3];
                float4 h4 = hrow[4], h5 = hrow[5], h6 = hrow[6], h7 = hrow[7];
                float oc[8] = {oa.x,oa.y,oa.z,oa.w, ob.x,ob.y,ob.z,ob.w};
                const float* w0 = &Wi01[k*64];
                #pragma unroll
                for (int c = 0; c < 8; ++c)
                    #pragma unroll
                    for (int d = 0; d < 8; ++d) ac[d] = fmaf(oc[c], w0[c*8 + d], ac[d]);
                float hc[32] = {h0.x,h0.y,h0.z,h0.w, h1.x,h1.y,h1.z,h1.w,
                                h2.x,h2.y,h2.z,h2.w, h3.x,h3.y,h3.z,h3.w,
                                h4.x,h4.y,h4.z,h4.w, h5.x,h5.y,h5.z,h5.w,
                                h6.x,h6.y,h6.z,h6.w, h7.x,h7.y,h7.z,h7.w};
                const float* w1 = &Wi10[k*256];
                #pragma unroll
                for (int c = 0; c < 32; ++c)
                    #pragma unroll
                    for (int d = 0; d < 8; ++d) ac[8+d] = fmaf(hc[c], w1[c*8 + d], ac[8+d]);
            }
        }
    }
    if (q > 0) {
        #pragma unroll
        for (int d = 0; d < 16; ++d) part[q-1][d][lane] = ac[d];
    }
    __syncthreads();
    if (q == 0) {
        #pragma unroll
        for (int d = 0; d < 8; ++d) {
            ac[d]   = fmaxf(ac[d]   + bi01[d] + part[0][d][lane]   + part[1][d][lane]   + part[2][d][lane],   0.f);
            ac[8+d] = fmaxf(ac[8+d] + bi10[d] + part[0][8+d][lane] + part[1][8+d][lane] + part[2][8+d][lane], 0.f);
        }
        float4* p0 = (float4*)(o0a + (size_t)n*8);
        p0[0] = make_float4(ac[0], ac[1], ac[2],  ac[3]);
        p0[1] = make_float4(ac[4], ac[5], ac[6],  ac[7]);
        float4* p1 = (float4*)(o1a + (size_t)n*8);
        p1[0] = make_float4(ac[8], ac[9], ac[10], ac[11]);
        p1[1] = make_float4(ac[12],ac[13],ac[14], ac[15]);
    }
}

// o1 = relu(conv(o1a, Wi11)+bi11) (8->16); o0 = relu(o0a@Wi02+bi02) (8->16)
// blk = relu([o0,o1] + h); out = blk @ W_conv1 + b_conv1 (epilogue 4-way split)
__global__ __launch_bounds__(256, 4) void k_out(const int* __restrict__ nbr3,
                                                const float* __restrict__ h,
                                                const float* __restrict__ o0a,
                                                const float* __restrict__ o1a,
                                                const float* __restrict__ Wi11,
                                                const float* __restrict__ bi11,
                                                const float* __restrict__ Wi02,
                                                const float* __restrict__ bi02,
                                                const float* __restrict__ W_conv1,
                                                const float* __restrict__ b_conv1,
                                                float* __restrict__ out) {
    __shared__ int   ln[64*27];          // 6.9KB
    __shared__ float part[3][16][64];    // 12KB
    __shared__ float blkb[32][64];       // 8KB
    int tid = threadIdx.x;
    int lane = tid & 63, q = tid >> 6;
    int n0 = blockIdx.x * 64;
    for (int i = tid; i < 64*27; i += 256) ln[i] = nbr3[(size_t)n0*27 + i];
    __syncthreads();
    int kbase = __builtin_amdgcn_readfirstlane(q * 7);
    int n = n0 + lane;
    int idxs[7];
    #pragma unroll
    for (int j = 0; j < 7; ++j) {
        int k = kbase + j;
        int kk = (k < 27) ? k : 26;
        int raw = ln[lane*27 + kk];
        idxs[j] = (k < 27) ? raw : NPTS;
    }
    float ac[16];
    #pragma unroll
    for (int d = 0; d < 16; ++d) ac[d] = 0.f;
    #pragma unroll
    for (int j = 0; j < 7; ++j) {
        int k = kbase + j;
        if (k < 27) {
            int idx = idxs[j];
            if (idx < NPTS) {
                const float4* rp = (const float4*)(o1a + (size_t)idx*8);
                float4 ra = rp[0], rb = rp[1];
                float rc[8] = {ra.x,ra.y,ra.z,ra.w, rb.x,rb.y,rb.z,rb.w};
                const float* wr = &Wi11[k*128];
                #pragma unroll
                for (int c = 0; c < 8; ++c)
                    #pragma unroll
                    for (int d = 0; d < 16; ++d) ac[d] = fmaf(rc[c], wr[c*16 + d], ac[d]);
            }
        }
    }
    if (q > 0) {
        #pragma unroll
        for (int d = 0; d < 16; ++d) part[q-1][d][lane] = ac[d];
    }
    __syncthreads();
    if (q == 0) {
        #pragma unroll
        for (int d = 0; d < 16; ++d)
            ac[d] += bi11[d] + part[0][d][lane] + part[1][d][lane] + part[2][d][lane];
        float blk[32];
        const float4* prow = (const float4*)(o0a + (size_t)n*8);
        float4 pa = prow[0], pb = prow[1];
        float pc[8] = {pa.x,pa.y,pa.z,pa.w, pb.x,pb.y,pb.z,pb.w};
        #pragma unroll
        for (int j = 0; j < 16; ++j) {
            float tt = bi02[j];
            #pragma unroll
            for (int c = 0; c < 8; ++c) tt = fmaf(pc[c], Wi02[c*16 + j], tt);
            blk[j] = fmaxf(tt, 0.f);                 // o0
        }
        #pragma unroll
        for (int j = 0; j < 16; ++j) blk[16+j] = fmaxf(ac[j], 0.f);   // o1
        const float4* hrow = (const float4*)(h + (size_t)n*32);
        #pragma unroll
        for (int w = 0; w < 8; ++w) {
            float4 hv = hrow[w];
            blk[w*4+0] += hv.x; blk[w*4+1] += hv.y; blk[w*4+2] += hv.z; blk[w*4+3] += hv.w;
        }
        #pragma unroll
        for (int e = 0; e < 32; ++e) blkb[e][lane] = fmaxf(blk[e], 0.f);
    }
    __syncthreads();
    int q8 = __builtin_amdgcn_readfirstlane(q * 8);  // out-channel base for this wave
    float oacc[8];
    #pragma unroll
    for (int d = 0; d < 8; ++d) oacc[d] = b_conv1[q8 + d];
    #pragma unroll
    for (int e = 0; e < 32; ++e) {
        float bl = blkb[e][lane];
        #pragma unroll
        for (int d = 0; d < 8; ++d) oacc[d] = fmaf(bl, W_conv1[e*32 + q8 + d], oacc[d]);
    }
    float4* outp = (float4*)(out + (size_t)n*32 + q8);
    outp[0] = make_float4(oacc[0], oacc[1], oacc[2], oacc[3]);
    outp[1] = make_float4(oacc[4], oacc[5], oacc[6], oacc[7]);
}

extern "C" void kernel_launch(void* const* d_in, const int* in_sizes, int n_in,
                              void* d_out, int out_size, void* d_ws, size_t ws_size,
                              hipStream_t stream) {
    (void)in_sizes; (void)n_in; (void)out_size; (void)ws_size;
    const float* prev_F   = (const float*)d_in[0];
    const int*   prev_C   = (const int*)d_in[1];
    const int*   cur_C    = (const int*)d_in[2];
    // d_in[3] = nbr_interp  (unused: reconstructed via dense grid)
    const int*   nbr3     = (const int*)d_in[4];
    // d_in[5] = knn_idx     (unused: attention branch is exactly zero)
    const float* W_interp = (const float*)d_in[6];
    const float* b_interp = (const float*)d_in[7];
    const float* W_conv0  = (const float*)d_in[8];
    const float* b_conv0  = (const float*)d_in[9];
    const float* W_conv1  = (const float*)d_in[10];
    const float* b_conv1  = (const float*)d_in[11];
    const float* Wi00     = (const float*)d_in[12];
    const float* bi00     = (const float*)d_in[13];
    const float* Wi01     = (const float*)d_in[14];
    const float* bi01     = (const float*)d_in[15];
    const float* Wi02     = (const float*)d_in[16];
    const float* bi02     = (const float*)d_in[17];
    const float* Wi10     = (const float*)d_in[18];
    const float* bi10     = (const float*)d_in[19];
    const float* Wi11     = (const float*)d_in[20];
    const float* bi11     = (const float*)d_in[21];
    // d_in[22..33]: attention + LN params, all unused (branch == 0 exactly)

    float* ws    = (float*)d_ws;
    float* gridF = ws;                      // 373248 floats (72^3)
    int*   pidg  = (int*)(ws + 373248);     // 262144 ints (cell -> pid+1; 0=empty)
    float* ctx   = ws + 635392;             // 65536
    float* h     = ws + 700928;             // 65536*32
    float* o     = ws + 2798080;            // 65536*8
    float* o0a   = ws + 3322368;            // 65536*8
    float* o1a   = ws + 3846656;            // 65536*8  (end: 4370944 floats = 16.7 MB)
    float* outp  = (float*)d_out;

    // gridF needs 0.0f, pidg needs 0 (=empty) -> one fill covers both.
    hipMemsetAsync(gridF, 0, (GRID_FLOATS + CELLS)*sizeof(float), stream);
    k_scatter  <<<NPTS/256, 256, 0, stream>>>(prev_F, prev_C, cur_C, gridF, pidg);
    k_ctx_dense<<<512,      256, 0, stream>>>(gridF, pidg, W_interp, b_interp, ctx);
    k_conv0    <<<NPTS/64,  256, 0, stream>>>(nbr3, ctx, W_conv0, b_conv0, Wi00, bi00, h, o);
    k_mid      <<<NPTS/64,  256, 0, stream>>>(nbr3, h, o, Wi01, bi01, Wi10, bi10, o0a, o1a);
    k_out      <<<NPTS/64,  256, 0, stream>>>(nbr3, h, o0a, o1a, Wi11, bi11, Wi02, bi02, W_conv1, b_conv1, outp);
}